// Round 2
// 269.726 us; speedup vs baseline: 1.0566x; 1.0566x over previous
//
#include <hip/hip_runtime.h>

// XOR-conv as implicit-GEMM MFMA (bf16 inputs, fp32 accum).
// out[b,co,ho,wo] = sum_{ci,kh,kw} x[b,ci,ho+kh,wo+kw] * (1-2*W[co,ci,kh,kw])
// Shapes: B=32, CI=128, H=W=64, CO=256, K=3, HO=WO=62.
//
// R3 (resubmit; previous run died to an infra flake, not a kernel fault):
// wave owns 2 output rows x 4 co-tiles (af reuse 4->8 MFMA/load, W L2
// traffic halved to 0.59 GB); af double-buffered one tap ahead (prefetch walks
// linear [cc][e] prepack layout, crosses the cc barrier to hide under staging);
// staging packs ci-quads and writes ds_write_b64 (8 banks, half the instrs).

typedef __bf16 bf16x8 __attribute__((ext_vector_type(8)));
typedef float  f32x4  __attribute__((ext_vector_type(4)));

#define CIPAD 40  // 32-ci chunk padded to 40 ushorts (80B col stride; frag reads 2-way = free)

// ---- prepack: W fp32 [co][ci][3][3] in {0,1} -> bf16 bits in A-frag order ----
// layout: [g=cc*9+e (36)][tile(16)][lane(64)][j(8)]  (ushort)
//   co = tile*16 + (lane&15), ci = cc*32 + (lane>>4)*8 + j, e = kh*3+kw
__global__ void prepack_w_kernel(const float* __restrict__ Wf,
                                 unsigned short* __restrict__ effw) {
  int idx = blockIdx.x * 256 + threadIdx.x;     // 36*16*64*8 = 294912
  if (idx >= 36 * 16 * 64 * 8) return;
  int j    = idx & 7;
  int lane = (idx >> 3) & 63;
  int tile = (idx >> 9) & 15;
  int g    = idx >> 13;          // cc*9 + e, 0..35
  int e    = g % 9;
  int cc   = g / 9;
  int co = tile * 16 + (lane & 15);
  int ci = cc * 32 + (lane >> 4) * 8 + j;
  float w = Wf[(co * 128 + ci) * 9 + e];
  __bf16 h = (__bf16)(1.0f - 2.0f * w);         // exactly +-1
  unsigned short u; __builtin_memcpy(&u, &h, 2);
  effw[idx] = u;
}

__device__ __forceinline__ unsigned int pack_bf16(float a, float b) {
  __bf16 ha = (__bf16)a, hb = (__bf16)b;
  unsigned short ua, ub;
  __builtin_memcpy(&ua, &ha, 2);
  __builtin_memcpy(&ub, &hb, 2);
  return (unsigned)ua | ((unsigned)ub << 16);
}

// Block: 256 threads = 4 waves. Tile: 64 co x (8 output rows x 64 virtual cols).
// Wave wv owns output rows {2wv, 2wv+1}, 4 co 16-tiles, 4 col 16-tiles.
__global__ __launch_bounds__(256, 2)
void xorconv_mfma_kernel(const float* __restrict__ x,
                         const unsigned short* __restrict__ effw,
                         float* __restrict__ out) {
  __shared__ __align__(16) unsigned short xs[10 * 66 * CIPAD];  // 52.8 KB

  const int tid    = threadIdx.x;
  const int bxc    = blockIdx.x;         // co quarter: 0..3
  const int co_blk = bxc * 64;
  const int hbase  = blockIdx.y * 8;     // 0..56
  const int bb     = blockIdx.z;         // batch

  const int wv   = tid >> 6;
  const int lane = tid & 63;
  const int quad = lane >> 4;
  const int l16  = lane & 15;

  f32x4 acc[2][4][4];
  #pragma unroll
  for (int rw = 0; rw < 2; ++rw)
    #pragma unroll
    for (int i = 0; i < 4; ++i)
      #pragma unroll
      for (int j = 0; j < 4; ++j)
        acc[rw][i][j] = (f32x4){0.f, 0.f, 0.f, 0.f};

  unsigned int* xs32 = (unsigned int*)xs;

  // ---- af double-buffer: preload (cc=0, e=0) ----
  const unsigned short* wbase = effw + ((size_t)(bxc * 4) * 64 + lane) * 8;
  bf16x8 afb[2][4];
  #pragma unroll
  for (int mt = 0; mt < 4; ++mt)
    afb[0][mt] = *(const bf16x8*)(wbase + mt * 512);

  for (int cc = 0; cc < 4; ++cc) {
    const int c0 = cc * 32;

    // ---- stage x tile: ci in [c0,c0+32), rows hbase..hbase+9, cols 0..65 ----
    // thread handles a ci-quad (4 planes) x 2 cols -> two ds_write_b64.
    for (int p = tid; p < 10 * 33 * 8; p += 256) {
      int c2 = p % 33;
      int t  = p / 33;       // 0..79
      int cp = t & 7;        // ci-quad: planes c0+4cp .. c0+4cp+3
      int r  = t >> 3;       // 0..9
      int c  = c2 * 2;
      int h_in = hbase + r; if (h_in > 63) h_in = 63;  // clamp: feeds only masked outputs
      int c_in = c;         if (c_in > 62) c_in = 62;
      const float* gp = x + ((size_t)(bb * 128 + c0 + cp * 4) * 4096 + h_in * 64 + c_in);
      float a0 = gp[0],     a1 = gp[1];
      float b0 = gp[4096],  b1 = gp[4097];
      float e0 = gp[8192],  e1 = gp[8193];
      float g0 = gp[12288], g1 = gp[12289];
      uint2 w0 = {pack_bf16(a0, b0), pack_bf16(e0, g0)};   // col c,   ci 4cp..4cp+3
      uint2 w1 = {pack_bf16(a1, b1), pack_bf16(e1, g1)};   // col c+1
      *(uint2*)&xs32[(r * 66 + c)     * (CIPAD / 2) + cp * 2] = w0;
      *(uint2*)&xs32[(r * 66 + c + 1) * (CIPAD / 2) + cp * 2] = w1;
    }
    __syncthreads();   // xs ready

    // ---- 9 filter taps; af for tap e+1 prefetched while tap e computes ----
    #pragma unroll
    for (int e = 0; e < 9; ++e) {
      const int cur = e & 1, nxt = cur ^ 1;
      const int kh = e / 3, kw = e % 3;

      {
        int lin  = cc * 9 + e;
        int linn = lin < 35 ? lin + 1 : 35;    // clamped re-load on the very last tap
        const unsigned short* wp = wbase + (size_t)linn * 8192;
        #pragma unroll
        for (int mt = 0; mt < 4; ++mt)
          afb[nxt][mt] = *(const bf16x8*)(wp + mt * 512);
      }

      #pragma unroll
      for (int rw = 0; rw < 2; ++rw) {
        const int rr = wv * 2 + rw + kh;       // 0..9
        bf16x8 bfr[4];
        #pragma unroll
        for (int j = 0; j < 4; ++j) {
          int ccol = j * 16 + l16 + kw;        // 0..65
          bfr[j] = *(const bf16x8*)&xs[(rr * 66 + ccol) * CIPAD + quad * 8];
        }
        #pragma unroll
        for (int mt = 0; mt < 4; ++mt)
          #pragma unroll
          for (int j = 0; j < 4; ++j)
            acc[rw][mt][j] = __builtin_amdgcn_mfma_f32_16x16x32_bf16(
                afb[cur][mt], bfr[j], acc[rw][mt][j], 0, 0, 0);
      }
    }
    __syncthreads();   // taps done before next chunk overwrites xs

    // e=8 prefetched (cc+1, e=0) into afb[1]; next cc expects it in afb[0]
    #pragma unroll
    for (int mt = 0; mt < 4; ++mt) afb[0][mt] = afb[1][mt];
  }

  // ---- epilogue: C/D layout col(n)=lane&15, row(m)=quad*4+reg ----
  #pragma unroll
  for (int rw = 0; rw < 2; ++rw) {
    const int ho = hbase + wv * 2 + rw;
    if (ho < 62) {
      #pragma unroll
      for (int mt = 0; mt < 4; ++mt) {
        const int co = co_blk + mt * 16 + quad * 4;
        #pragma unroll
        for (int j = 0; j < 4; ++j) {
          const int wo = j * 16 + l16;
          if (wo < 62) {
            float* op = out + (((size_t)(bb * 256 + co) * 62 + ho) * 62 + wo);
            #pragma unroll
            for (int rg = 0; rg < 4; ++rg)
              op[(size_t)rg * 3844] = acc[rw][mt][j][rg];
          }
        }
      }
    }
  }
}

extern "C" void kernel_launch(void* const* d_in, const int* in_sizes, int n_in,
                              void* d_out, int out_size, void* d_ws, size_t ws_size,
                              hipStream_t stream) {
  const float* x  = (const float*)d_in[0];
  const float* Wf = (const float*)d_in[1];
  float* out = (float*)d_out;
  unsigned short* effw = (unsigned short*)d_ws;   // 36*16*64*8*2 B scratch

  prepack_w_kernel<<<dim3((36 * 16 * 64 * 8 + 255) / 256), dim3(256), 0, stream>>>(Wf, effw);

  dim3 grid(4, 8, 32);   // co-quarters x ho-tiles(8 rows) x batch
  xorconv_mfma_kernel<<<grid, dim3(256), 0, stream>>>(x, effw, out);
}

// Round 3
// 242.408 us; speedup vs baseline: 1.1757x; 1.1127x over previous
//
#include <hip/hip_runtime.h>

// XOR-conv as implicit-GEMM MFMA (bf16 inputs, fp32 accum).
// out[b,co,ho,wo] = sum_{ci,kh,kw} x[b,ci,ho+kh,wo+kw] * (1-2*W[co,ci,kh,kw])
// Shapes: B=32, CI=128, H=W=64, CO=256, K=3, HO=WO=62.
//
// R4: x pre-packed once to bf16 in LDS-image order with baked bank swizzle
// (ci-oct slot q' = q ^ (w&3)); conv staging = 10 uint4 copies/thread/cc
// (no in-loop cvt/pack); swizzled ds_read spreads 2-way over 16 banks;
// XCD-aware block remap co-locates the 4 co-quarter blocks per x-window.

typedef __bf16 bf16x8 __attribute__((ext_vector_type(8)));
typedef float  f32x4  __attribute__((ext_vector_type(4)));

// ---- prepack W: fp32 [co][ci][3][3] in {0,1} -> bf16 bits in A-frag order ----
// layout: [g=cc*9+e (36)][tile(16)][lane(64)][j(8)]  (ushort)
//   co = tile*16 + (lane&15), ci = cc*32 + (lane>>4)*8 + j, e = kh*3+kw
__global__ void prepack_w_kernel(const float* __restrict__ Wf,
                                 unsigned short* __restrict__ effw) {
  int idx = blockIdx.x * 256 + threadIdx.x;     // 36*16*64*8 = 294912
  if (idx >= 36 * 16 * 64 * 8) return;
  int j    = idx & 7;
  int lane = (idx >> 3) & 63;
  int tile = (idx >> 9) & 15;
  int g    = idx >> 13;          // cc*9 + e, 0..35
  int e    = g % 9;
  int cc   = g / 9;
  int co = tile * 16 + (lane & 15);
  int ci = cc * 32 + (lane >> 4) * 8 + j;
  float w = Wf[(co * 128 + ci) * 9 + e];
  __bf16 h = (__bf16)(1.0f - 2.0f * w);         // exactly +-1
  unsigned short u; __builtin_memcpy(&u, &h, 2);
  effw[idx] = u;
}

// ---- prepack x: fp32 [b][ci][h][w] -> bf16 ushort xp[b][cc][h][w][q'][8ci]
// where the oct at slot q' holds ci = cc*32 + q*8 + 0..7 with q = q' ^ (w&3).
// Writes are perfectly coalesced 16B/thread; reads coalesce per (q,k)-plane.
__global__ void prepack_x_kernel(const float* __restrict__ x,
                                 unsigned short* __restrict__ xp) {
  int idx = blockIdx.x * 256 + threadIdx.x;     // 32*4*64*64*4 = 2097152 exact
  int qp = idx & 3;
  int w  = (idx >> 2) & 63;
  int h  = (idx >> 8) & 63;
  int cc = (idx >> 14) & 3;
  int b  = idx >> 16;
  int q  = qp ^ (w & 3);
  const float* xb = x + (((size_t)(b * 128 + cc * 32 + q * 8)) * 64 + h) * 64 + w;
  unsigned short o[8];
  #pragma unroll
  for (int k = 0; k < 8; ++k) {
    float f = xb[(size_t)k * 4096];
    __bf16 hh = (__bf16)f;
    unsigned short u; __builtin_memcpy(&u, &hh, 2);
    o[k] = u;
  }
  unsigned int w0 = (unsigned)o[0] | ((unsigned)o[1] << 16);
  unsigned int w1 = (unsigned)o[2] | ((unsigned)o[3] << 16);
  unsigned int w2 = (unsigned)o[4] | ((unsigned)o[5] << 16);
  unsigned int w3 = (unsigned)o[6] | ((unsigned)o[7] << 16);
  uint4 v = {w0, w1, w2, w3};
  *(uint4*)(xp + (size_t)idx * 8) = v;
}

// Block: 256 threads = 4 waves. Tile: 64 co x (8 output rows x 64 virtual cols).
// Wave wv owns output rows {2wv, 2wv+1}, 4 co 16-tiles, 4 col 16-tiles.
// LDS row: 66 cols x 32 ushorts (cols 64-65 garbage, feed only masked outputs).
__global__ __launch_bounds__(256, 2)
void xorconv_mfma_kernel(const unsigned short* __restrict__ xp,
                         const unsigned short* __restrict__ effw,
                         float* __restrict__ out) {
  __shared__ __align__(16) unsigned short xs[10 * 66 * 32];  // 42.2 KB

  const int tid = threadIdx.x;

  // XCD-aware remap: lin%8 is the XCD (round-robin); give each XCD a
  // contiguous chunk so the 4 co-quarters of one x-window share one L2.
  const int lin  = blockIdx.x + 4 * blockIdx.y + 32 * blockIdx.z;  // 0..1023
  const int work = (lin & 7) * 128 + (lin >> 3);                   // bijective
  const int bxc   = work & 3;          // co quarter: 0..3
  const int hbt   = (work >> 2) & 7;   // ho tile
  const int bb    = work >> 5;         // batch
  const int co_blk = bxc * 64;
  const int hbase  = hbt * 8;          // 0..56

  const int wv   = tid >> 6;
  const int lane = tid & 63;
  const int quad = lane >> 4;
  const int l16  = lane & 15;

  f32x4 acc[2][4][4];
  #pragma unroll
  for (int rw = 0; rw < 2; ++rw)
    #pragma unroll
    for (int i = 0; i < 4; ++i)
      #pragma unroll
      for (int j = 0; j < 4; ++j)
        acc[rw][i][j] = (f32x4){0.f, 0.f, 0.f, 0.f};

  // ---- af double-buffer: preload (cc=0, e=0) ----
  const unsigned short* wbase = effw + ((size_t)(bxc * 4) * 64 + lane) * 8;
  bf16x8 afb[2][4];
  #pragma unroll
  for (int mt = 0; mt < 4; ++mt)
    afb[0][mt] = *(const bf16x8*)(wbase + mt * 512);

  for (int cc = 0; cc < 4; ++cc) {
    // ---- stage: 10 rows, each row = 4096B contiguous global -> LDS copy ----
    const unsigned short* xpcc = xp + ((size_t)(bb * 4 + cc) * 64) * 2048;
    #pragma unroll
    for (int r = 0; r < 10; ++r) {
      int h_in = hbase + r; if (h_in > 63) h_in = 63;  // uniform clamp: masked rows
      *(uint4*)&xs[r * 2112 + tid * 8] =
          *(const uint4*)(xpcc + (size_t)h_in * 2048 + tid * 8);
    }
    __syncthreads();   // xs ready

    // ---- 9 filter taps; af for tap e+1 prefetched while tap e computes ----
    #pragma unroll
    for (int e = 0; e < 9; ++e) {
      const int cur = e & 1, nxt = cur ^ 1;
      const int kh = e / 3, kw = e % 3;

      {
        int lin2  = cc * 9 + e;
        int linn  = lin2 < 35 ? lin2 + 1 : 35;   // clamped re-load on last tap
        const unsigned short* wp = wbase + (size_t)linn * 8192;
        #pragma unroll
        for (int mt = 0; mt < 4; ++mt)
          afb[nxt][mt] = *(const bf16x8*)(wp + mt * 512);
      }

      #pragma unroll
      for (int rw = 0; rw < 2; ++rw) {
        const int rr = wv * 2 + rw + kh;       // 0..9
        bf16x8 bfr[4];
        #pragma unroll
        for (int j = 0; j < 4; ++j) {
          int ccol = j * 16 + l16 + kw;        // 0..65
          int slot = quad ^ (ccol & 3);        // inverse of prepack swizzle
          bfr[j] = *(const bf16x8*)&xs[rr * 2112 + ccol * 32 + slot * 8];
        }
        #pragma unroll
        for (int mt = 0; mt < 4; ++mt)
          #pragma unroll
          for (int j = 0; j < 4; ++j)
            acc[rw][mt][j] = __builtin_amdgcn_mfma_f32_16x16x32_bf16(
                afb[cur][mt], bfr[j], acc[rw][mt][j], 0, 0, 0);
      }
    }
    __syncthreads();   // taps done before next chunk overwrites xs

    // e=8 prefetched (cc+1, e=0) into afb[nxt]=afb[1]; next cc expects afb[0]
    #pragma unroll
    for (int mt = 0; mt < 4; ++mt) afb[0][mt] = afb[1][mt];
  }

  // ---- epilogue: C/D layout col(n)=lane&15, row(m)=quad*4+reg ----
  #pragma unroll
  for (int rw = 0; rw < 2; ++rw) {
    const int ho = hbase + wv * 2 + rw;
    if (ho < 62) {
      #pragma unroll
      for (int mt = 0; mt < 4; ++mt) {
        const int co = co_blk + mt * 16 + quad * 4;
        #pragma unroll
        for (int j = 0; j < 4; ++j) {
          const int wo = j * 16 + l16;
          if (wo < 62) {
            float* op = out + (((size_t)(bb * 256 + co) * 62 + ho) * 62 + wo);
            #pragma unroll
            for (int rg = 0; rg < 4; ++rg)
              op[(size_t)rg * 3844] = acc[rw][mt][j][rg];
          }
        }
      }
    }
  }
}

extern "C" void kernel_launch(void* const* d_in, const int* in_sizes, int n_in,
                              void* d_out, int out_size, void* d_ws, size_t ws_size,
                              hipStream_t stream) {
  const float* x  = (const float*)d_in[0];
  const float* Wf = (const float*)d_in[1];
  float* out = (float*)d_out;
  // workspace: xp (33.55 MB) then effw (0.59 MB)
  unsigned short* xp   = (unsigned short*)d_ws;
  unsigned short* effw = xp + (size_t)16777216;   // 32*4*64*64*4*8

  prepack_x_kernel<<<dim3(8192), dim3(256), 0, stream>>>(x, xp);
  prepack_w_kernel<<<dim3((36 * 16 * 64 * 8 + 255) / 256), dim3(256), 0, stream>>>(Wf, effw);

  dim3 grid(4, 8, 32);   // linearized+remapped inside the kernel
  xorconv_mfma_kernel<<<grid, dim3(256), 0, stream>>>(xp, effw, out);
}

// Round 5
// 236.952 us; speedup vs baseline: 1.2027x; 1.0230x over previous
//
#include <hip/hip_runtime.h>

// XOR-conv as implicit-GEMM MFMA (bf16 inputs, fp32 accum).
// out[b,co,ho,wo] = sum_{ci,kh,kw} x[b,ci,ho+kh,wo+kw] * (1-2*W[co,ci,kh,kw])
// Shapes: B=32, CI=128, H=W=64, CO=256, K=3, HO=WO=62.
//
// R5 (resubmit; container death was infra, kernel audits clean):
// 2-phase pipelined cc loop (T3-minimum): double-buffered xs (4 out rows,
// 6 staged, 49.5KB total), stage(cc+1) via global_load_lds width=16 issued
// before compute(cc), ONE barrier per cc. 3 blocks/CU (launch_bounds 256,3).
// af prefetch distance 2 (ring of 3). Prepack x+W merged into one launch.

typedef __bf16 bf16x8 __attribute__((ext_vector_type(8)));
typedef float  f32x4  __attribute__((ext_vector_type(4)));

#define GLOADLDS16(gp, lp)                                                    \
  __builtin_amdgcn_global_load_lds(                                           \
      (const __attribute__((address_space(1))) unsigned int*)(gp),            \
      (__attribute__((address_space(3))) unsigned int*)(lp), 16, 0, 0)

// ---- merged prepack ----
// blocks [0,8192): x fp32 [b][ci][h][w] -> bf16 xp[b][cc][h][w][q'][8ci],
//   oct slot q' holds ci = cc*32 + q*8 + 0..7 with q = q' ^ (w&3)  (bank swz).
// blocks [8192,9344): W fp32 [co][ci][3][3] {0,1} -> effw A-frag order
//   [g=cc*9+e (36)][tile(16)][lane(64)][j(8)]:
//   co = tile*16 + (lane&15), ci = cc*32 + (lane>>4)*8 + j, e = kh*3+kw
__global__ void prepack_kernel(const float* __restrict__ x,
                               const float* __restrict__ Wf,
                               unsigned short* __restrict__ xp,
                               unsigned short* __restrict__ effw) {
  if (blockIdx.x < 8192) {
    int idx = blockIdx.x * 256 + threadIdx.x;   // 32*4*64*64*4 = 2097152 exact
    int qp = idx & 3;
    int w  = (idx >> 2) & 63;
    int h  = (idx >> 8) & 63;
    int cc = (idx >> 14) & 3;
    int b  = idx >> 16;
    int q  = qp ^ (w & 3);
    const float* xb = x + (((size_t)(b * 128 + cc * 32 + q * 8)) * 64 + h) * 64 + w;
    unsigned short o[8];
    #pragma unroll
    for (int k = 0; k < 8; ++k) {
      float f = xb[(size_t)k * 4096];
      __bf16 hh = (__bf16)f;
      unsigned short u; __builtin_memcpy(&u, &hh, 2);
      o[k] = u;
    }
    uint4 v = {(unsigned)o[0] | ((unsigned)o[1] << 16),
               (unsigned)o[2] | ((unsigned)o[3] << 16),
               (unsigned)o[4] | ((unsigned)o[5] << 16),
               (unsigned)o[6] | ((unsigned)o[7] << 16)};
    *(uint4*)(xp + (size_t)idx * 8) = v;
  } else {
    int idx = (blockIdx.x - 8192) * 256 + threadIdx.x;  // 36*16*64*8 = 294912 exact
    int j    = idx & 7;
    int lane = (idx >> 3) & 63;
    int tile = (idx >> 9) & 15;
    int g    = idx >> 13;        // cc*9 + e
    int e    = g % 9;
    int cc   = g / 9;
    int co = tile * 16 + (lane & 15);
    int ci = cc * 32 + (lane >> 4) * 8 + j;
    float w = Wf[(co * 128 + ci) * 9 + e];
    __bf16 h = (__bf16)(1.0f - 2.0f * w);       // exactly +-1
    unsigned short u; __builtin_memcpy(&u, &h, 2);
    effw[idx] = u;
  }
}

// Block: 256 threads = 4 waves. Tile: 64 co x (4 output rows x 64 virtual cols).
// Wave wv owns output row hbase+wv, 4 co 16-tiles, 4 col 16-tiles.
// LDS row: 66 cols x 32 ushorts; cols 64-65 uninitialized (feed masked lanes only).
__global__ __launch_bounds__(256, 3)
void xorconv_mfma_kernel(const unsigned short* __restrict__ xp,
                         const unsigned short* __restrict__ effw,
                         float* __restrict__ out) {
  __shared__ __align__(16) unsigned short xs[2][6 * 66 * 32];  // 49.5 KB

  const int tid = threadIdx.x;

  // XCD-aware remap: each XCD gets a contiguous work chunk so the 4 co-quarter
  // blocks of one x-window (and adjacent row tiles) share one L2.
  const int lin  = blockIdx.x;                       // 0..2047
  const int work = (lin & 7) * 256 + (lin >> 3);     // bijective (2048 = 8*256)
  const int bxc   = work & 3;          // co quarter
  const int hbt   = (work >> 2) & 15;  // ho tile (4 rows)
  const int bb    = work >> 6;         // batch
  const int co_blk = bxc * 64;
  const int hbase  = hbt * 4;          // 0..60

  const int wv   = tid >> 6;
  const int lane = tid & 63;
  const int quad = lane >> 4;
  const int l16  = lane & 15;

  f32x4 acc[4][4];
  #pragma unroll
  for (int i = 0; i < 4; ++i)
    #pragma unroll
    for (int j = 0; j < 4; ++j)
      acc[i][j] = (f32x4){0.f, 0.f, 0.f, 0.f};

  // ---- af ring (distance-2 prefetch): preload g=0,1 ----
  const unsigned short* wbase = effw + ((size_t)(bxc * 4) * 64 + lane) * 8;
  bf16x8 afb[3][4];
  #pragma unroll
  for (int g = 0; g < 2; ++g)
    #pragma unroll
    for (int mt = 0; mt < 4; ++mt)
      afb[g][mt] = *(const bf16x8*)(wbase + (size_t)g * 8192 + mt * 512);

  const unsigned short* xpb = xp + (size_t)(bb * 4) * 64 * 2048;

  // ---- prologue: stage cc=0 into xs[0] ----
  #pragma unroll
  for (int k = 0; k < 6; ++k) {
    int h_in = hbase + k; if (h_in > 63) h_in = 63;  // clamp: feeds masked rows
    GLOADLDS16(xpb + (size_t)h_in * 2048 + tid * 8,
               &xs[0][k * 2112 + tid * 8]);
  }
  __syncthreads();   // vmcnt(0) drain: buf0 ready

  #pragma unroll
  for (int cc = 0; cc < 4; ++cc) {
    // ---- issue stage(cc+1) into the other buffer; lands during compute ----
    if (cc < 3) {
      const unsigned short* s = xpb + (size_t)((cc + 1) * 64) * 2048;
      #pragma unroll
      for (int k = 0; k < 6; ++k) {
        int h_in = hbase + k; if (h_in > 63) h_in = 63;
        GLOADLDS16(s + (size_t)h_in * 2048 + tid * 8,
                   &xs[(cc + 1) & 1][k * 2112 + tid * 8]);
      }
    }

    // ---- compute cc from current buffer: 9 taps ----
    const unsigned short* xb = xs[cc & 1];
    #pragma unroll
    for (int e = 0; e < 9; ++e) {
      const int g  = cc * 9 + e;
      const int kh = e / 3, kw = e % 3;

      if (g + 2 <= 35) {                       // prefetch af two taps ahead
        const unsigned short* wp = wbase + (size_t)(g + 2) * 8192;
        #pragma unroll
        for (int mt = 0; mt < 4; ++mt)
          afb[(g + 2) % 3][mt] = *(const bf16x8*)(wp + mt * 512);
      }

      const int rr = wv + kh;                  // 0..5
      bf16x8 bfr[4];
      #pragma unroll
      for (int j = 0; j < 4; ++j) {
        int ccol = j * 16 + l16 + kw;          // 0..65
        int slot = quad ^ (ccol & 3);          // inverse of prepack swizzle
        bfr[j] = *(const bf16x8*)&xb[rr * 2112 + ccol * 32 + slot * 8];
      }
      #pragma unroll
      for (int mt = 0; mt < 4; ++mt)
        #pragma unroll
        for (int j = 0; j < 4; ++j)
          acc[mt][j] = __builtin_amdgcn_mfma_f32_16x16x32_bf16(
              afb[g % 3][mt], bfr[j], acc[mt][j], 0, 0, 0);
    }
    __syncthreads();   // drains stage(cc+1) DMA; protects buffer swap
  }

  // ---- epilogue: C/D layout col(n)=lane&15, row(m)=quad*4+reg ----
  const int ho = hbase + wv;
  if (ho < 62) {
    #pragma unroll
    for (int mt = 0; mt < 4; ++mt) {
      const int co = co_blk + mt * 16 + quad * 4;
      #pragma unroll
      for (int j = 0; j < 4; ++j) {
        const int wo = j * 16 + l16;
        if (wo < 62) {
          float* op = out + (((size_t)(bb * 256 + co) * 62 + ho) * 62 + wo);
          #pragma unroll
          for (int rg = 0; rg < 4; ++rg)
            op[(size_t)rg * 3844] = acc[mt][j][rg];
        }
      }
    }
  }
}

extern "C" void kernel_launch(void* const* d_in, const int* in_sizes, int n_in,
                              void* d_out, int out_size, void* d_ws, size_t ws_size,
                              hipStream_t stream) {
  const float* x  = (const float*)d_in[0];
  const float* Wf = (const float*)d_in[1];
  float* out = (float*)d_out;
  // workspace: xp (33.55 MB) then effw (0.59 MB)
  unsigned short* xp   = (unsigned short*)d_ws;
  unsigned short* effw = xp + (size_t)16777216;   // 32*4*64*64*4*8

  prepack_kernel<<<dim3(8192 + 1152), dim3(256), 0, stream>>>(x, Wf, xp, effw);

  dim3 grid(2048);   // (co-quarter x ho-tile x batch), XCD-remapped in-kernel
  xorconv_mfma_kernel<<<grid, dim3(256), 0, stream>>>(xp, effw, out);
}